// Round 4
// baseline (304.011 us; speedup 1.0000x reference)
//
#include <hip/hip_runtime.h>

// images=8, patches=3600(=60*60), hor_f=64, ver_f=25(=5*5), 64x64 px, k=5
#define KW     5
#define OH     60
#define NIMG   8
#define HF     64
#define VF     25
#define NPATCH 3600
#define CDIM   1600                  // HF*VF

// ---- fold: direct gather + LDS f32-atomic accumulate, partial strips to slab ----
// grid (hg=8, g=15, im=8); block 256. Block owns pi in [4g,4g+4), h in [8hg,8hg+8),
// accumulates strip rows i in [4g, 4g+8) x 8 h x 64 j, writes to slab (no atomics).
// slab layout: [(g*8+im)][ch 64][i_l 8][j 64]  (only ch-section [h0,h0+8) written
// by each hg block; union over hg covers all 64 ch). 120*64*8*64 fl = 15.7 MB.

#define OLPAD 70
#define OLSZ  (8 * 8 * OLPAD)        // strip accumulator: [i_l 8][h_l 8][70]

__global__ __launch_bounds__(256) void fold_kernel(const float* __restrict__ x,
                                                   float* __restrict__ slab) {
    __shared__ float ol[OLSZ];
    __shared__ __align__(16) int tab[200];
    const int hg = blockIdx.x;       // 0..7
    const int g  = blockIdx.y;       // 0..14
    const int im = blockIdx.z;       // 0..7
    const int t  = threadIdx.x;
    const int h0 = hg * 8;

    for (int u = t; u < OLSZ; u += 256) ol[u] = 0.f;
    if (t < 200) {                   // c = h_l*25 + di*5 + dj  ->  strip slot offset
        int h_l = t / 25, v = t % 25, di = v / 5, dj = v - 5 * di;
        tab[t] = (di * 8 + h_l) * OLPAD + dj;
    }
    __syncthreads();

    // 240 patches (4 pi rows x 60 pj), 200 floats each (8 h x 25 v, contiguous)
    const float* xb = x + ((size_t)im * NPATCH + 240 * g) * CDIM + h0 * VF;
    for (int u = t; u < 12000; u += 256) {      // 240 patches * 50 float4
        int p_l = u / 50, c4 = u - p_l * 50;
        int pi_l = p_l / 60, pj = p_l - pi_l * 60;
        float4 xv = *reinterpret_cast<const float4*>(xb + (size_t)p_l * CDIM + c4 * 4);
        int base = pi_l * (8 * OLPAD) + pj;     // slot = ((pi_l+di)*8+h_l)*70 + pj+dj
        int4 of = *reinterpret_cast<const int4*>(&tab[c4 * 4]);
        atomicAdd(&ol[base + of.x], xv.x);      // ds_add_f32
        atomicAdd(&ol[base + of.y], xv.y);
        atomicAdd(&ol[base + of.z], xv.z);
        atomicAdd(&ol[base + of.w], xv.w);
    }
    __syncthreads();

    // strip -> slab, coalesced float4 stores
    float* sb = slab + (((size_t)(g * 8 + im) * 64 + h0) * 8) * 64;
    for (int m = t; m < 1024; m += 256) {       // 8h * 8i * 16 j4
        int j4 = m & 15, i_l = (m >> 4) & 7, h_l = m >> 7;
        int a = (i_l * 8 + h_l) * OLPAD + j4 * 4;
        float4 v;
        v.x = ol[a]; v.y = ol[a + 1]; v.z = ol[a + 2]; v.w = ol[a + 3];
        *reinterpret_cast<float4*>(sb + ((size_t)h_l * 8 + i_l) * 64 + j4 * 4) = v;
    }
}

// ---- unfold: stage (summed) strip rows into LDS, divide by count, f4 writes ----
// grid (hg2=2, pi=60, im=8); block 256. Row i gets strips from groups
// g in [max(0,(i-4)>>2), min(14, i>>2)]  (1 or 2 groups, disjoint pi coverage).
#define LIPAD 68

__global__ __launch_bounds__(256) void unfold_kernel(const float* __restrict__ slab,
                                                     float* __restrict__ out) {
    __shared__ float li[32 * 5 * LIPAD];        // [ch_l 32][di 5][68] = 43.5 KB
    __shared__ float rcp_tab[25];
    const int hg = blockIdx.x;       // 0..1
    const int pi = blockIdx.y;       // 0..59
    const int im = blockIdx.z;       // 0..7
    const int t  = threadIdx.x;
    const int h0 = hg * 32;

    if (t < 25) rcp_tab[t] = 1.0f / (float)((t / 5 + 1) * (t % 5 + 1));

    for (int u = t; u < 2560; u += 256) {       // 32 ch * 5 di * 16 j4
        int ch_l = u / 80, rem = u - ch_l * 80;
        int di = rem >> 4, jf = rem & 15;
        int i = pi + di;                        // <= 63
        int g_lo = max(0, (i - 4) >> 2);
        int g_hi = min(14, i >> 2);
        const float* pa = slab + ((((size_t)(g_lo * 8 + im)) * 64 + h0 + ch_l) * 8
                                  + (i - 4 * g_lo)) * 64 + jf * 4;
        float4 v = *reinterpret_cast<const float4*>(pa);
        if (g_hi != g_lo) {
            const float* pb = slab + ((((size_t)(g_hi * 8 + im)) * 64 + h0 + ch_l) * 8
                                      + (i - 4 * g_hi)) * 64 + jf * 4;
            float4 w = *reinterpret_cast<const float4*>(pb);
            v.x += w.x; v.y += w.y; v.z += w.z; v.w += w.w;
        }
        *reinterpret_cast<float4*>(&li[(ch_l * 5 + di) * LIPAD + jf * 4]) = v;
    }
    __syncthreads();

    // out chunk for (im, pi, h-range): 60 pj * (32 h * 25 v) floats, contiguous per pj
    float* ob = out + ((size_t)im * NPATCH + (size_t)pi * OH) * CDIM + h0 * VF;
    for (int u = t; u < 12000; u += 256) {      // 60 pj * 200 f4
        int pj = u / 200, r = u - pj * 200;
        float4 o;
        float* op = &o.x;
#pragma unroll
        for (int e = 0; e < 4; ++e) {
            int fl = 4 * r + e;                 // 0..799 = h_off*25 + v
            int h_off = fl / 25, v = fl - 25 * h_off;
            int di = v / 5, dj = v - 5 * di;
            int i = pi + di, j = pj + dj;
            float val = li[(h_off * 5 + di) * LIPAD + j];
            int ci = min(min(i + 1, 64 - i), 5);
            int cj = min(min(j + 1, 64 - j), 5);
            op[e] = val * rcp_tab[(ci - 1) * 5 + (cj - 1)];
        }
        *reinterpret_cast<float4*>(ob + (size_t)pj * CDIM + 4 * r) = o;
    }
}

extern "C" void kernel_launch(void* const* d_in, const int* in_sizes, int n_in,
                              void* d_out, int out_size, void* d_ws, size_t ws_size,
                              hipStream_t stream) {
    const float* x = (const float*)d_in[0];
    float* slab = (float*)d_ws;                 // 3,932,160 floats = 15.7 MB
    float* out  = (float*)d_out;

    fold_kernel<<<dim3(8, 15, NIMG), 256, 0, stream>>>(x, slab);
    unfold_kernel<<<dim3(2, OH, NIMG), 256, 0, stream>>>(slab, out);

    (void)out_size; (void)ws_size; (void)in_sizes; (void)n_in;
}

// Round 5
// 108.492 us; speedup vs baseline: 2.8022x; 2.8022x over previous
//
#include <hip/hip_runtime.h>

// images=8, patches=3600(=60*60), hor_f=64, ver_f=25(=5*5), 64x64 px, k=5
#define OH     60
#define NIMG   8
#define HF     64
#define VF     25
#define NPATCH 3600
#define CDIM   1600                  // HF*VF

// ---- fold: grid (hg 8, strip 12, im 8) = 768 blocks, 512 threads ----
#define FH   8                       // h channels per block
#define FC   (FH * VF)               // 200 c values
#define SPI  5                       // pi rows per strip
#define PJS  64                      // padded pj stride (XOR-swizzled)

__global__ __launch_bounds__(512) void zero_kernel(float4* __restrict__ img) {
    img[blockIdx.x * 512u + threadIdx.x] = float4{0.f, 0.f, 0.f, 0.f};
}

__global__ __launch_bounds__(512) void fold_kernel(const float* __restrict__ x,
                                                   float* __restrict__ img) {
    __shared__ float lb[FC * PJS];   // 200*64 = 12800 fl = 51.2 KB
    const int hg = blockIdx.x, strip = blockIdx.y, im = blockIdx.z;
    const int t = threadIdx.x;
    const int h0 = hg * FH;
    const int pi0 = strip * SPI;
    const int j = t & 63, g = t >> 6;          // g = local h (0..7)

    float acc[SPI + 4];
#pragma unroll
    for (int k = 0; k < SPI + 4; ++k) acc[k] = 0.f;

    const float* xb = x + ((size_t)im * NPATCH + (size_t)pi0 * OH) * CDIM + h0 * VF;

#pragma unroll
    for (int row = 0; row < SPI; ++row) {
        if (row) __syncthreads();              // prev-row readers done
        // stage row: 60 patches x 50 float4 (contiguous 800B per patch)
        for (int u = t; u < 3000; u += 512) {
            int pj = u / 50, c4 = u - 50 * pj;
            float4 v = *reinterpret_cast<const float4*>(
                xb + (size_t)row * OH * CDIM + (size_t)pj * CDIM + (c4 << 2));
            int pjs = pj ^ (c4 & 31);          // write banks = (pj^c4)&31: all 32
            int a = c4 * (4 * PJS) + pjs;
            lb[a]           = v.x;
            lb[a + PJS]     = v.y;
            lb[a + 2 * PJS] = v.z;
            lb[a + 3 * PJS] = v.w;
        }
        __syncthreads();
        // compute: lane j, h=g fixed; reads are lane-consecutive ^ const -> conflict-free
#pragma unroll
        for (int di = 0; di < 5; ++di) {
#pragma unroll
            for (int dj = 0; dj < 5; ++dj) {
                int c = g * VF + di * 5 + dj;
                int pjr = j - dj;
                if ((unsigned)pjr < 60u)
                    acc[row + di] += lb[c * PJS + (pjr ^ ((c >> 2) & 31))];
            }
        }
    }

    // epilogue: complete rows stored, boundary rows atomic onto zeroed img
    const int n = (im << 6) + h0 + g;
    float* ib = img + ((size_t)n << 12) + j;
#pragma unroll
    for (int il = 0; il < SPI + 4; ++il) {
        int i = pi0 + il;
        bool direct = (il >= 4 || pi0 == 0) && (il <= 4 || pi0 == 55);
        float* p = ib + (i << 6);
        if (direct) *p = acc[il];
        else        atomicAdd(p, acc[il]);
    }
}

// ---- unfold: grid (hh 2, pi 60, im 8) = 960 blocks, 256 threads ----
#define LJS 68                       // f4-aligned padded j stride, XOR-swizzled

__global__ __launch_bounds__(256) void unfold_kernel(const float* __restrict__ img,
                                                     float* __restrict__ out) {
    __shared__ float li[32 * 5 * LJS];         // 10880 fl = 43.5 KB
    const int hh = blockIdx.x;                 // 0..1
    const int pi = blockIdx.y;                 // 0..59
    const int im = blockIdx.z;
    const int t = threadIdx.x;
    const int h0 = hh << 5;

    // stage rows pi..pi+4 of 32 channels, pre-scaled by 1/(ci*cj)
    for (int u = t; u < 2560; u += 256) {
        int ch = u / 80, rem = u - 80 * ch;
        int di = rem >> 4, j4 = rem & 15;
        int i = pi + di;
        int n = (im << 6) + h0 + ch;
        float4 v = *reinterpret_cast<const float4*>(
            img + ((size_t)n << 12) + (i << 6) + (j4 << 2));
        float ri = 1.0f / (float)min(min(i + 1, 64 - i), 5);
        int jb = j4 << 2;
        float4 w;
        w.x = v.x * ri * (1.0f / (float)min(min(jb + 1, 64 - jb), 5));
        w.y = v.y * ri * (1.0f / (float)min(min(jb + 2, 63 - jb), 5));
        w.z = v.z * ri * (1.0f / (float)min(min(jb + 3, 62 - jb), 5));
        w.w = v.w * ri * (1.0f / (float)min(min(jb + 4, 61 - jb), 5));
        int R = ch * 5 + di;
        int z4 = R & 7;                        // f4-unit swizzle
        *reinterpret_cast<float4*>(&li[R * LJS + ((j4 ^ z4) << 2)]) = w;
    }
    __syncthreads();

    // emit: 60 pj x 200 float4, fully coalesced writes; li already scaled
    float* ob = out + ((size_t)im * NPATCH + (size_t)pi * OH) * CDIM + h0 * VF;
    for (int u = t; u < 12000; u += 256) {
        int pj = u / 200, r = u - 200 * pj;
        float4 o;
        float* op = &o.x;
#pragma unroll
        for (int e = 0; e < 4; ++e) {
            int fl = 4 * r + e;                // = ho*25 + v
            int ho = fl / 25, v = fl - 25 * ho;
            int di = v / 5, dj = v - 5 * di;
            int jj = pj + dj;
            int R = ho * 5 + di;
            op[e] = li[R * LJS + (jj ^ ((R & 7) << 2))];
        }
        *reinterpret_cast<float4*>(ob + (size_t)pj * CDIM + 4 * r) = o;
    }
}

extern "C" void kernel_launch(void* const* d_in, const int* in_sizes, int n_in,
                              void* d_out, int out_size, void* d_ws, size_t ws_size,
                              hipStream_t stream) {
    const float* x = (const float*)d_in[0];
    float* img = (float*)d_ws;                 // 512*64*64 fl = 8.4 MB
    float* out = (float*)d_out;

    zero_kernel<<<1024, 512, 0, stream>>>((float4*)img);            // 2M floats
    fold_kernel<<<dim3(8, 12, NIMG), 512, 0, stream>>>(x, img);     // 768 blocks
    unfold_kernel<<<dim3(2, OH, NIMG), 256, 0, stream>>>(img, out); // 960 blocks

    (void)out_size; (void)ws_size; (void)in_sizes; (void)n_in;
}

// Round 6
// 101.690 us; speedup vs baseline: 2.9896x; 1.0669x over previous
//
#include <hip/hip_runtime.h>

// images=8, patches=3600(=60*60), hor_f=64, ver_f=25(=5*5), 64x64 px, k=5
#define OH     60
#define NIMG   8
#define HF     64
#define VF     25
#define NPATCH 3600
#define CDIM   1600                  // HF*VF

// ---- fold: grid (hg 8, strip 12, im 8) = 768 blocks, 512 threads ----
#define FH   8                       // h channels per block
#define FC   (FH * VF)               // 200 c values
#define SPI  5                       // pi rows per strip
#define PJS  64                      // padded pj stride (XOR-swizzled)

__global__ __launch_bounds__(512) void zero_kernel(float4* __restrict__ img) {
    img[blockIdx.x * 512u + threadIdx.x] = float4{0.f, 0.f, 0.f, 0.f};
}

__global__ __launch_bounds__(512) void fold_kernel(const float* __restrict__ x,
                                                   float* __restrict__ img) {
    __shared__ float lb[FC * PJS];   // 200*64 = 12800 fl = 51.2 KB
    const int hg = blockIdx.x, strip = blockIdx.y, im = blockIdx.z;
    const int t = threadIdx.x;
    const int h0 = hg * FH;
    const int pi0 = strip * SPI;
    const int j = t & 63, g = t >> 6;          // g = local h (0..7)

    float acc[SPI + 4];
#pragma unroll
    for (int k = 0; k < SPI + 4; ++k) acc[k] = 0.f;

    const float* xb = x + ((size_t)im * NPATCH + (size_t)pi0 * OH) * CDIM + h0 * VF;

#pragma unroll
    for (int row = 0; row < SPI; ++row) {
        if (row) __syncthreads();              // prev-row readers done
        // stage row: 60 patches x 50 float4 (contiguous 800B per patch)
        for (int u = t; u < 3000; u += 512) {
            int pj = u / 50, c4 = u - 50 * pj;
            float4 v = *reinterpret_cast<const float4*>(
                xb + (size_t)row * OH * CDIM + (size_t)pj * CDIM + (c4 << 2));
            int pjs = pj ^ (c4 & 31);          // write banks = (pj^c4)&31: all 32
            int a = c4 * (4 * PJS) + pjs;
            lb[a]           = v.x;
            lb[a + PJS]     = v.y;
            lb[a + 2 * PJS] = v.z;
            lb[a + 3 * PJS] = v.w;
        }
        __syncthreads();
        // compute: lane j, h=g fixed; reads are lane-consecutive ^ const -> conflict-free
#pragma unroll
        for (int di = 0; di < 5; ++di) {
#pragma unroll
            for (int dj = 0; dj < 5; ++dj) {
                int c = g * VF + di * 5 + dj;
                int pjr = j - dj;
                if ((unsigned)pjr < 60u)
                    acc[row + di] += lb[c * PJS + (pjr ^ ((c >> 2) & 31))];
            }
        }
    }

    // epilogue: complete rows stored, boundary rows atomic onto zeroed img
    const int n = (im << 6) + h0 + g;
    float* ib = img + ((size_t)n << 12) + j;
#pragma unroll
    for (int il = 0; il < SPI + 4; ++il) {
        int i = pi0 + il;
        bool direct = (il >= 4 || pi0 == 0) && (il <= 4 || pi0 == 55);
        float* p = ib + (i << 6);
        if (direct) *p = acc[il];
        else        atomicAdd(p, acc[il]);
    }
}

// ---- unfold v2: grid (hh 4, pi 60, im 8) = 1920 blocks, 256 threads ----
// LDS: li[R=ch*5+di][j] pre-scaled by 1/(ci*cj); emit driven by int4 offset LUT.
#define UH   16                      // channels per block
#define LJS  68                      // padded j stride (f4-aligned)

__global__ __launch_bounds__(256) void unfold_kernel(const float* __restrict__ img,
                                                     float* __restrict__ out) {
    __shared__ float li[UH * 5 * LJS];         // 5440 fl = 21.76 KB
    __shared__ int4 lut[100];
    const int hh = blockIdx.x;                 // 0..3
    const int pi = blockIdx.y;                 // 0..59
    const int im = blockIdx.z;
    const int t = threadIdx.x;
    const int h0 = hh * UH;

    if (t < 100) {                             // f4-slot r -> 4 LDS offsets (R*LJS+dj)
        int4 e;
        int* ep = &e.x;
#pragma unroll
        for (int k = 0; k < 4; ++k) {
            int fl = 4 * t + k;                // = ho*25 + v
            int ho = fl / 25, v = fl - 25 * ho;
            int di = v / 5, dj = v - 5 * di;
            ep[k] = (ho * 5 + di) * LJS + dj;
        }
        lut[t] = e;
    }

    // stage rows pi..pi+4 of 16 channels, pre-scaled by 1/(ci*cj)
    for (int u = t; u < UH * 5 * 16; u += 256) {
        int ch = u / 80, rem = u - 80 * ch;
        int di = rem >> 4, j4 = rem & 15;
        int i = pi + di;
        int n = (im << 6) + h0 + ch;
        float4 v = *reinterpret_cast<const float4*>(
            img + ((size_t)n << 12) + (i << 6) + (j4 << 2));
        float ri = 1.0f / (float)min(min(i + 1, 64 - i), 5);
        int jb = j4 << 2;
        float4 w;
        w.x = v.x * ri * (1.0f / (float)min(min(jb + 1, 64 - jb), 5));
        w.y = v.y * ri * (1.0f / (float)min(min(jb + 2, 63 - jb), 5));
        w.z = v.z * ri * (1.0f / (float)min(min(jb + 3, 62 - jb), 5));
        w.w = v.w * ri * (1.0f / (float)min(min(jb + 4, 61 - jb), 5));
        *reinterpret_cast<float4*>(&li[(ch * 5 + di) * LJS + jb]) = w;
    }
    __syncthreads();

    // emit: 60 pj x 100 float4 (16h x 25v per pj), LUT-addressed, coalesced writes
    float* ob = out + ((size_t)im * NPATCH + (size_t)pi * OH) * CDIM + h0 * VF;
    for (int u = t; u < 6000; u += 256) {
        int pj = u / 100, r = u - 100 * pj;
        int4 e = lut[r];
        float4 o;
        o.x = li[e.x + pj];
        o.y = li[e.y + pj];
        o.z = li[e.z + pj];
        o.w = li[e.w + pj];
        *reinterpret_cast<float4*>(ob + (size_t)pj * CDIM + 4 * r) = o;
    }
}

extern "C" void kernel_launch(void* const* d_in, const int* in_sizes, int n_in,
                              void* d_out, int out_size, void* d_ws, size_t ws_size,
                              hipStream_t stream) {
    const float* x = (const float*)d_in[0];
    float* img = (float*)d_ws;                 // 512*64*64 fl = 8.4 MB
    float* out = (float*)d_out;

    zero_kernel<<<1024, 512, 0, stream>>>((float4*)img);            // 2M floats
    fold_kernel<<<dim3(8, 12, NIMG), 512, 0, stream>>>(x, img);     // 768 blocks
    unfold_kernel<<<dim3(4, OH, NIMG), 256, 0, stream>>>(img, out); // 1920 blocks

    (void)out_size; (void)ws_size; (void)in_sizes; (void)n_in;
}

// Round 7
// 101.529 us; speedup vs baseline: 2.9943x; 1.0016x over previous
//
#include <hip/hip_runtime.h>

// images=8, patches=3600(=60*60), hor_f=64, ver_f=25(=5*5), 64x64 px, k=5
#define OH     60
#define NIMG   8
#define HF     64
#define VF     25
#define NPATCH 3600
#define CDIM   1600                  // HF*VF

// ---- fold: grid (hg 8, strip 12, im 8) = 768 blocks, 512 threads ----
#define FH   8                       // h channels per block
#define FC   (FH * VF)               // 200 c values
#define SPI  5                       // pi rows per strip
#define PJS  64                      // pj stride (XOR-swizzled)

__global__ __launch_bounds__(512) void zero_kernel(float4* __restrict__ img) {
    img[blockIdx.x * 512u + threadIdx.x] = float4{0.f, 0.f, 0.f, 0.f};
}

__global__ __launch_bounds__(512, 6) void fold_kernel(const float* __restrict__ x,
                                                      float* __restrict__ img) {
    __shared__ float lb[FC * PJS];   // 200*64 = 12800 fl = 51.2 KB
    const int hg = blockIdx.x, strip = blockIdx.y, im = blockIdx.z;
    const int t = threadIdx.x;
    const int h0 = hg * FH;
    const int pi0 = strip * SPI;
    const int j = t & 63, g = t >> 6;          // g = local h (0..7)

    float acc[SPI + 4];
#pragma unroll
    for (int k = 0; k < SPI + 4; ++k) acc[k] = 0.f;

    const float* xb = x + ((size_t)im * NPATCH + (size_t)pi0 * OH) * CDIM + h0 * VF;

    // row-invariant per-thread staging offsets (u = t + 512k, active if u < 3000)
    int off_g[6], off_l[6];
#pragma unroll
    for (int k = 0; k < 6; ++k) {
        int u = t + 512 * k;
        if (u < 3000) {
            int pj = u / 50, c4 = u - 50 * pj;
            off_g[k] = pj * CDIM + (c4 << 2);              // float offset in row-chunk
            off_l[k] = (c4 << 8) + (pj ^ (c4 & 31));       // LDS word addr (bank-spread)
        }
    }

    float4 stg[6];
    // prologue: load row 0 into registers
#pragma unroll
    for (int k = 0; k < 6; ++k)
        if (t + 512 * k < 3000)
            stg[k] = *reinterpret_cast<const float4*>(xb + off_g[k]);

#pragma unroll
    for (int row = 0; row < SPI; ++row) {
        if (row) __syncthreads();              // previous row's readers done
        // write staged registers -> LDS
#pragma unroll
        for (int k = 0; k < 6; ++k)
            if (t + 512 * k < 3000) {
                float4 v = stg[k];
                int a = off_l[k];
                lb[a]           = v.x;
                lb[a + PJS]     = v.y;
                lb[a + 2 * PJS] = v.z;
                lb[a + 3 * PJS] = v.w;
            }
        // issue next row's loads now; waited on only at next iteration's ds_write
        if (row + 1 < SPI) {
#pragma unroll
            for (int k = 0; k < 6; ++k)
                if (t + 512 * k < 3000)
                    stg[k] = *reinterpret_cast<const float4*>(
                        xb + (size_t)(row + 1) * OH * CDIM + off_g[k]);
        }
        __syncthreads();
        // compute: lane j, h=g fixed; 2-way bank aliasing only (free)
#pragma unroll
        for (int di = 0; di < 5; ++di) {
#pragma unroll
            for (int dj = 0; dj < 5; ++dj) {
                int c = g * VF + di * 5 + dj;
                int pjr = j - dj;
                if ((unsigned)pjr < 60u)
                    acc[row + di] += lb[c * PJS + (pjr ^ ((c >> 2) & 31))];
            }
        }
    }

    // epilogue: complete rows stored, boundary rows atomic onto zeroed img
    const int n = (im << 6) + h0 + g;
    float* ib = img + ((size_t)n << 12) + j;
#pragma unroll
    for (int il = 0; il < SPI + 4; ++il) {
        int i = pi0 + il;
        bool direct = (il >= 4 || pi0 == 0) && (il <= 4 || pi0 == 55);
        float* p = ib + (i << 6);
        if (direct) *p = acc[il];
        else        atomicAdd(p, acc[il]);
    }
}

// ---- unfold: grid (hh 4, pi 60, im 8) = 1920 blocks, 256 threads ----
#define UH   16                      // channels per block
#define LJS  68                      // padded j stride (f4-aligned)

__global__ __launch_bounds__(256) void unfold_kernel(const float* __restrict__ img,
                                                     float* __restrict__ out) {
    __shared__ float li[UH * 5 * LJS];         // 5440 fl = 21.76 KB
    __shared__ int4 lut[100];
    const int hh = blockIdx.x;                 // 0..3
    const int pi = blockIdx.y;                 // 0..59
    const int im = blockIdx.z;
    const int t = threadIdx.x;
    const int h0 = hh * UH;

    if (t < 100) {                             // f4-slot r -> 4 LDS offsets (R*LJS+dj)
        int4 e;
        int* ep = &e.x;
#pragma unroll
        for (int k = 0; k < 4; ++k) {
            int fl = 4 * t + k;                // = ho*25 + v
            int ho = fl / 25, v = fl - 25 * ho;
            int di = v / 5, dj = v - 5 * di;
            ep[k] = (ho * 5 + di) * LJS + dj;
        }
        lut[t] = e;
    }

    // stage rows pi..pi+4 of 16 channels, pre-scaled by 1/(ci*cj)
    for (int u = t; u < UH * 5 * 16; u += 256) {
        int ch = u / 80, rem = u - 80 * ch;
        int di = rem >> 4, j4 = rem & 15;
        int i = pi + di;
        int n = (im << 6) + h0 + ch;
        float4 v = *reinterpret_cast<const float4*>(
            img + ((size_t)n << 12) + (i << 6) + (j4 << 2));
        float ri = 1.0f / (float)min(min(i + 1, 64 - i), 5);
        int jb = j4 << 2;
        float4 w;
        w.x = v.x * ri * (1.0f / (float)min(min(jb + 1, 64 - jb), 5));
        w.y = v.y * ri * (1.0f / (float)min(min(jb + 2, 63 - jb), 5));
        w.z = v.z * ri * (1.0f / (float)min(min(jb + 3, 62 - jb), 5));
        w.w = v.w * ri * (1.0f / (float)min(min(jb + 4, 61 - jb), 5));
        *reinterpret_cast<float4*>(&li[(ch * 5 + di) * LJS + jb]) = w;
    }
    __syncthreads();

    // emit: 60 pj x 100 float4 (16h x 25v per pj), LUT-addressed, coalesced writes
    float* ob = out + ((size_t)im * NPATCH + (size_t)pi * OH) * CDIM + h0 * VF;
    for (int u = t; u < 6000; u += 256) {
        int pj = u / 100, r = u - 100 * pj;
        int4 e = lut[r];
        float4 o;
        o.x = li[e.x + pj];
        o.y = li[e.y + pj];
        o.z = li[e.z + pj];
        o.w = li[e.w + pj];
        *reinterpret_cast<float4*>(ob + (size_t)pj * CDIM + 4 * r) = o;
    }
}

extern "C" void kernel_launch(void* const* d_in, const int* in_sizes, int n_in,
                              void* d_out, int out_size, void* d_ws, size_t ws_size,
                              hipStream_t stream) {
    const float* x = (const float*)d_in[0];
    float* img = (float*)d_ws;                 // 512*64*64 fl = 8.4 MB
    float* out = (float*)d_out;

    zero_kernel<<<1024, 512, 0, stream>>>((float4*)img);            // 2M floats
    fold_kernel<<<dim3(8, 12, NIMG), 512, 0, stream>>>(x, img);     // 768 blocks
    unfold_kernel<<<dim3(4, OH, NIMG), 256, 0, stream>>>(img, out); // 1920 blocks

    (void)out_size; (void)ws_size; (void)in_sizes; (void)n_in;
}

// Round 8
// 96.786 us; speedup vs baseline: 3.1410x; 1.0490x over previous
//
#include <hip/hip_runtime.h>

// images=8, patches=3600(=60*60), hor_f=64, ver_f=25(=5*5), 64x64 px, k=5
#define OH     60
#define NIMG   8
#define HF     64
#define VF     25
#define NPATCH 3600
#define CDIM   1600                  // HF*VF

// ---- fold: grid (hg 8, strip 12, im 8) = 768 blocks, 512 threads ----
// Block owns pi rows [5s, 5s+5) and writes rows i in [5s, 5s+9) (incl. halo) of
// its 8-channel slice into slab[s][im][ch][il][j]  (plain stores, disjoint).
#define FH   8                       // h channels per block
#define FC   (FH * VF)               // 200 c values
#define SPI  5                       // pi rows per strip
#define PJS  64                      // pj stride (XOR-swizzled)
#define NSTRIP 12
#define SROWS  9                     // SPI + 4 halo rows

__global__ __launch_bounds__(512, 6) void fold_kernel(const float* __restrict__ x,
                                                      float* __restrict__ slab) {
    __shared__ float lb[FC * PJS];   // 200*64 = 12800 fl = 51.2 KB
    const int hg = blockIdx.x, strip = blockIdx.y, im = blockIdx.z;
    const int t = threadIdx.x;
    const int h0 = hg * FH;
    const int pi0 = strip * SPI;
    const int j = t & 63, g = t >> 6;          // g = local h (0..7)

    float acc[SROWS];
#pragma unroll
    for (int k = 0; k < SROWS; ++k) acc[k] = 0.f;

    const float* xb = x + ((size_t)im * NPATCH + (size_t)pi0 * OH) * CDIM + h0 * VF;

    // row-invariant per-thread staging offsets (u = t + 512k, active if u < 3000)
    int off_g[6], off_l[6];
#pragma unroll
    for (int k = 0; k < 6; ++k) {
        int u = t + 512 * k;
        if (u < 3000) {
            int pj = u / 50, c4 = u - 50 * pj;
            off_g[k] = pj * CDIM + (c4 << 2);              // float offset in row-chunk
            off_l[k] = (c4 << 8) + (pj ^ (c4 & 31));       // LDS word addr (bank-spread)
        }
    }

    float4 stg[6];
#pragma unroll
    for (int k = 0; k < 6; ++k)
        if (t + 512 * k < 3000)
            stg[k] = *reinterpret_cast<const float4*>(xb + off_g[k]);

#pragma unroll
    for (int row = 0; row < SPI; ++row) {
        if (row) __syncthreads();              // previous row's readers done
#pragma unroll
        for (int k = 0; k < 6; ++k)
            if (t + 512 * k < 3000) {
                float4 v = stg[k];
                int a = off_l[k];
                lb[a]           = v.x;
                lb[a + PJS]     = v.y;
                lb[a + 2 * PJS] = v.z;
                lb[a + 3 * PJS] = v.w;
            }
        if (row + 1 < SPI) {                   // prefetch next row during compute
#pragma unroll
            for (int k = 0; k < 6; ++k)
                if (t + 512 * k < 3000)
                    stg[k] = *reinterpret_cast<const float4*>(
                        xb + (size_t)(row + 1) * OH * CDIM + off_g[k]);
        }
        __syncthreads();
#pragma unroll
        for (int di = 0; di < 5; ++di) {
#pragma unroll
            for (int dj = 0; dj < 5; ++dj) {
                int c = g * VF + di * 5 + dj;
                int pjr = j - dj;
                if ((unsigned)pjr < 60u)
                    acc[row + di] += lb[c * PJS + (pjr ^ ((c >> 2) & 31))];
            }
        }
    }

    // epilogue: 9 plain coalesced stores (256B/wave), disjoint slab region
    float* sb = slab + (((size_t)(strip * 8 + im) * 64 + h0 + g) * SROWS) * 64 + j;
#pragma unroll
    for (int il = 0; il < SROWS; ++il) sb[il * 64] = acc[il];
}

// ---- unfold: grid (hh 4, pi 60, im 8) = 1920 blocks, 256 threads ----
// Row i is the sum of slab strips s in [s_lo, s_hi] (1 or 2), summed at staging.
#define UH   16                      // channels per block
#define LJS  68                      // padded j stride (f4-aligned)

__global__ __launch_bounds__(256) void unfold_kernel(const float* __restrict__ slab,
                                                     float* __restrict__ out) {
    __shared__ float li[UH * 5 * LJS];         // 5440 fl = 21.76 KB
    __shared__ int4 lut[100];
    const int hh = blockIdx.x;                 // 0..3
    const int pi = blockIdx.y;                 // 0..59
    const int im = blockIdx.z;
    const int t = threadIdx.x;
    const int h0 = hh * UH;

    if (t < 100) {                             // f4-slot r -> 4 LDS offsets (R*LJS+dj)
        int4 e;
        int* ep = &e.x;
#pragma unroll
        for (int k = 0; k < 4; ++k) {
            int fl = 4 * t + k;                // = ho*25 + v
            int ho = fl / 25, v = fl - 25 * ho;
            int di = v / 5, dj = v - 5 * di;
            ep[k] = (ho * 5 + di) * LJS + dj;
        }
        lut[t] = e;
    }

    // stage rows pi..pi+4 of 16 channels (strip-summed), pre-scaled by 1/(ci*cj)
    for (int u = t; u < UH * 5 * 16; u += 256) {
        int ch = u / 80, rem = u - 80 * ch;
        int di = rem >> 4, j4 = rem & 15;
        int i = pi + di;
        int s_hi = min(i / 5, NSTRIP - 1);
        int s_lo = (i <= 8) ? 0 : (i - 4) / 5;
        const float* pa = slab +
            (((size_t)(s_lo * 8 + im) * 64 + h0 + ch) * SROWS + (i - 5 * s_lo)) * 64 + (j4 << 2);
        float4 v = *reinterpret_cast<const float4*>(pa);
        if (s_hi != s_lo) {
            const float* pb = slab +
                (((size_t)(s_hi * 8 + im) * 64 + h0 + ch) * SROWS + (i - 5 * s_hi)) * 64 + (j4 << 2);
            float4 w = *reinterpret_cast<const float4*>(pb);
            v.x += w.x; v.y += w.y; v.z += w.z; v.w += w.w;
        }
        float ri = 1.0f / (float)min(min(i + 1, 64 - i), 5);
        int jb = j4 << 2;
        float4 w;
        w.x = v.x * ri * (1.0f / (float)min(min(jb + 1, 64 - jb), 5));
        w.y = v.y * ri * (1.0f / (float)min(min(jb + 2, 63 - jb), 5));
        w.z = v.z * ri * (1.0f / (float)min(min(jb + 3, 62 - jb), 5));
        w.w = v.w * ri * (1.0f / (float)min(min(jb + 4, 61 - jb), 5));
        *reinterpret_cast<float4*>(&li[(ch * 5 + di) * LJS + jb]) = w;
    }
    __syncthreads();

    // emit: 60 pj x 100 float4 (16h x 25v per pj), LUT-addressed, coalesced writes
    float* ob = out + ((size_t)im * NPATCH + (size_t)pi * OH) * CDIM + h0 * VF;
    for (int u = t; u < 6000; u += 256) {
        int pj = u / 100, r = u - 100 * pj;
        int4 e = lut[r];
        float4 o;
        o.x = li[e.x + pj];
        o.y = li[e.y + pj];
        o.z = li[e.z + pj];
        o.w = li[e.w + pj];
        *reinterpret_cast<float4*>(ob + (size_t)pj * CDIM + 4 * r) = o;
    }
}

extern "C" void kernel_launch(void* const* d_in, const int* in_sizes, int n_in,
                              void* d_out, int out_size, void* d_ws, size_t ws_size,
                              hipStream_t stream) {
    const float* x = (const float*)d_in[0];
    float* slab = (float*)d_ws;                // 12*8*64*9*64 fl = 14.2 MB
    float* out  = (float*)d_out;

    fold_kernel<<<dim3(8, NSTRIP, NIMG), 512, 0, stream>>>(x, slab);  // 768 blocks
    unfold_kernel<<<dim3(4, OH, NIMG), 256, 0, stream>>>(slab, out);  // 1920 blocks

    (void)out_size; (void)ws_size; (void)in_sizes; (void)n_in;
}